// Round 1
// baseline (4055.849 us; speedup 1.0000x reference)
//
#include <hip/hip_runtime.h>
#include <math.h>

// VQ-VAE forward, fp32 baseline. MI355X / gfx950.
// Stages: prep -> conv1 -> conv2 -> conv3 -> vq_dist -> vq_reduce -> 4x(deconv1, deconv2)
// Workspace layout (floats):
//   [0)            h1  33,554,432  (reused per-chunk as g: 16,777,216)
//   [33554432)     h2  16,777,216
//   [50331648)     enc  4,194,304
//   [54525952)     qdec 4,194,304
//   [58720256)     w3T     16,384
//   [58736640)     dw2T    12,288
//   [58748928)     enorm    2,048
//   [58750976)     loss        16 (padded)
//   [58750992)     pscore 1,048,576
//   [59799568)     pidx   1,048,576 (int)
//   total 60,848,144 floats = 243.4 MB

#define LD4(p) (*(const float4*)(p))
#define FMA4(A, s, W) { A.x += (s)*(W).x; A.y += (s)*(W).y; A.z += (s)*(W).z; A.w += (s)*(W).w; }
#define STOREL(dst, A, BB) { float4 t_; t_.x = leaky((A).x + (BB).x); t_.y = leaky((A).y + (BB).y); \
                             t_.z = leaky((A).z + (BB).z); t_.w = leaky((A).w + (BB).w); *(float4*)(dst) = t_; }

__device__ __forceinline__ float leaky(float v) { return v >= 0.f ? v : 0.01f * v; }

// ---------------------------------------------------------------- prep
__global__ __launch_bounds__(256) void k_prep(const float* __restrict__ w3, const float* __restrict__ dw2,
                                              const float* __restrict__ emb,
                                              float* __restrict__ w3T, float* __restrict__ dw2T,
                                              float* __restrict__ enorm, float* __restrict__ loss) {
    int t = blockIdx.x * 256 + threadIdx.x;
    if (t == 0) loss[0] = 0.f;
    if (t < 16384) {                       // w3T[d][c] = w3[c][d]  (w3 is [1,1,256,64])
        int d = t >> 8, c = t & 255;
        w3T[d * 256 + c] = w3[c * 64 + d];
    }
    int u = t - 16384;                     // dw2T[kk][o][i] = dw2[kk][i][o]  (dw2 [4,4,256,3])
    if (u >= 0 && u < 12288) {
        int i = u & 255; int rest = u >> 8; int o = rest % 3; int kk = rest / 3;
        dw2T[(kk * 3 + o) * 256 + i] = dw2[(kk * 256 + i) * 3 + o];
    }
    int v = t - (16384 + 12288);           // enorm[k] = ||emb[k]||^2
    if (v >= 0 && v < 2048) {
        const float* e = emb + v * 64;
        float s = 0.f;
        #pragma unroll
        for (int h = 0; h < 64; ++h) s += e[h] * e[h];
        enorm[v] = s;
    }
}

// ---------------------------------------------------------------- conv1: x[16,256,256,3] -> h1[16,128,128,128]
// 4x4 s2 SAME (pad 1,1), leaky. Block: 128 threads (= out channels), 4 output pixels along x.
__global__ __launch_bounds__(128) void k_conv1(const float* __restrict__ x, const float* __restrict__ w1,
                                               const float* __restrict__ b1, float* __restrict__ h1) {
    __shared__ float smem[120]; // [iy 4][ix 10][c 3]
    int bx = blockIdx.x;
    int xg = bx & 31, y = (bx >> 5) & 127, b = bx >> 12;
    int x0 = xg << 2;
    int tid = threadIdx.x;
    if (tid < 120) {
        int c = tid % 3, sp = tid / 3;
        int iy = sp / 10, ix = sp - iy * 10;
        int gy = 2 * y - 1 + iy, gx = 2 * x0 - 1 + ix;
        float v = 0.f;
        if ((unsigned)gy < 256u && (unsigned)gx < 256u)
            v = x[((b * 256 + gy) * 256 + gx) * 3 + c];
        smem[tid] = v;
    }
    __syncthreads();
    int o = tid;
    float a0 = 0.f, a1 = 0.f, a2 = 0.f, a3 = 0.f;
    #pragma unroll
    for (int ky = 0; ky < 4; ++ky)
        #pragma unroll
        for (int kx = 0; kx < 4; ++kx)
            #pragma unroll
            for (int c = 0; c < 3; ++c) {
                float wv = w1[((ky * 4 + kx) * 3 + c) * 128 + o];
                a0 += smem[(ky * 10 + kx + 0) * 3 + c] * wv;
                a1 += smem[(ky * 10 + kx + 2) * 3 + c] * wv;
                a2 += smem[(ky * 10 + kx + 4) * 3 + c] * wv;
                a3 += smem[(ky * 10 + kx + 6) * 3 + c] * wv;
            }
    float bb = b1[o];
    int ob = ((b * 128 + y) * 128 + x0) * 128 + o;
    h1[ob]       = leaky(a0 + bb);
    h1[ob + 128] = leaky(a1 + bb);
    h1[ob + 256] = leaky(a2 + bb);
    h1[ob + 384] = leaky(a3 + bb);
}

// ---------------------------------------------------------------- conv2: h1 -> h2[16,64,64,256]
// 4x4 s2 SAME (pad 1,1), leaky. Block: 256 thr = 64 o-quads x 4 out rows; tile 4x4 px x 256 o.
__global__ __launch_bounds__(256) void k_conv2(const float* __restrict__ h1, const float* __restrict__ w2,
                                               const float* __restrict__ b2, float* __restrict__ h2) {
    __shared__ float smem[12800]; // [iy 10][ix 10][c 128]
    int bx = blockIdx.x;
    int tx = bx & 15, ty = (bx >> 4) & 15, b = bx >> 8;
    int x0 = tx << 2, y0 = ty << 2;
    int tid = threadIdx.x;
    #pragma unroll
    for (int j = 0; j < 50; ++j) {
        int e = j * 256 + tid;
        int c = e & 127, sp = e >> 7;
        int iy = sp / 10, ix = sp - iy * 10;
        int gy = 2 * y0 - 1 + iy, gx = 2 * x0 - 1 + ix;
        float v = 0.f;
        if ((unsigned)gy < 128u && (unsigned)gx < 128u)
            v = h1[((b * 128 + gy) * 128 + gx) * 128 + c];
        smem[e] = v;
    }
    __syncthreads();
    int og = (tid & 63) << 2;   // 4 consecutive out channels
    int pg = tid >> 6;          // out row within tile (wave-uniform)
    float4 a0 = {0,0,0,0}, a1 = a0, a2 = a0, a3 = a0;
    for (int kk = 0; kk < 16; ++kk) {
        int ky = kk >> 2, kx = kk & 3;
        const float* wb = w2 + (kk * 128) * 256 + og;
        int r = (2 * pg + ky) * 10 + kx;
        const float* p0 = smem + (r + 0) * 128;
        const float* p1 = smem + (r + 2) * 128;
        const float* p2 = smem + (r + 4) * 128;
        const float* p3 = smem + (r + 6) * 128;
        #pragma unroll 2
        for (int c = 0; c < 128; c += 4) {
            float4 w0 = LD4(wb + (c + 0) * 256);
            float4 w1v = LD4(wb + (c + 1) * 256);
            float4 w2v = LD4(wb + (c + 2) * 256);
            float4 w3v = LD4(wb + (c + 3) * 256);
            float4 i0 = LD4(p0 + c), i1 = LD4(p1 + c), i2 = LD4(p2 + c), i3 = LD4(p3 + c);
            FMA4(a0, i0.x, w0) FMA4(a0, i0.y, w1v) FMA4(a0, i0.z, w2v) FMA4(a0, i0.w, w3v)
            FMA4(a1, i1.x, w0) FMA4(a1, i1.y, w1v) FMA4(a1, i1.z, w2v) FMA4(a1, i1.w, w3v)
            FMA4(a2, i2.x, w0) FMA4(a2, i2.y, w1v) FMA4(a2, i2.z, w2v) FMA4(a2, i2.w, w3v)
            FMA4(a3, i3.x, w0) FMA4(a3, i3.y, w1v) FMA4(a3, i3.z, w2v) FMA4(a3, i3.w, w3v)
        }
    }
    float4 bb = LD4(b2 + og);
    int ob = ((b * 64 + (y0 + pg)) * 64 + x0) * 256 + og;
    STOREL(h2 + ob,       a0, bb)
    STOREL(h2 + ob + 256, a1, bb)
    STOREL(h2 + ob + 512, a2, bb)
    STOREL(h2 + ob + 768, a3, bb)
}

// ---------------------------------------------------------------- conv3: 1x1, h2 -> enc[16,64,64,64]
__global__ __launch_bounds__(256) void k_conv3(const float* __restrict__ h2, const float* __restrict__ w3T,
                                               const float* __restrict__ b3, float* __restrict__ enc) {
    __shared__ float smem[1024]; // 4 pixels x 256 ch
    int bx = blockIdx.x;
    int tid = threadIdx.x;
    *(float4*)(smem + tid * 4) = LD4(h2 + bx * 1024 + tid * 4);
    __syncthreads();
    int p = tid >> 6, d = tid & 63;
    const float* wrow = w3T + d * 256;
    const float* in = smem + p * 256;
    float s0 = 0.f, s1 = 0.f, s2 = 0.f, s3 = 0.f;
    #pragma unroll 4
    for (int c = 0; c < 256; c += 4) {
        float4 iv = LD4(in + c);
        float4 wv = LD4(wrow + c);
        s0 += iv.x * wv.x; s1 += iv.y * wv.y; s2 += iv.z * wv.z; s3 += iv.w * wv.w;
    }
    enc[bx * 256 + tid] = b3[d] + ((s0 + s1) + (s2 + s3));
}

// ---------------------------------------------------------------- vq distance: partial argmin per 128-code chunk
// row r=(b,w,c): f[h] = enc[b,h,w,c]. score = ||e||^2 - 2 f.e  (||f||^2 constant per row).
__global__ __launch_bounds__(256) void k_vqdist(const float* __restrict__ enc, const float* __restrict__ emb,
                                                const float* __restrict__ enorm,
                                                float* __restrict__ pscore, int* __restrict__ pidx) {
    __shared__ float ec[8192];   // 128 codes x 64
    __shared__ float en[128];
    int bx = blockIdx.x;
    int chunk = bx & 15, rowblk = bx >> 4;
    int tid = threadIdx.x;
    const float* esrc = emb + chunk * 8192;
    #pragma unroll
    for (int j = 0; j < 8; ++j) {
        int e = (j * 256 + tid) * 4;
        *(float4*)(ec + e) = LD4(esrc + e);
    }
    if (tid < 128) en[tid] = enorm[chunk * 128 + tid];
    __syncthreads();
    int row = rowblk * 256 + tid;
    int c = row & 63, w = (row >> 6) & 63, b = row >> 12;
    const float* fs = enc + b * 262144 + w * 64 + c;   // stride 4096 over h
    float f[64];
    #pragma unroll
    for (int h = 0; h < 64; ++h) f[h] = fs[h * 4096];
    float best = 3.4e38f; int bk = 0;
    for (int kl = 0; kl < 128; kl += 2) {
        const float* e0 = ec + (kl << 6);
        float d0 = 0.f, d1 = 0.f;
        #pragma unroll
        for (int h4 = 0; h4 < 16; ++h4) {
            float4 u = LD4(e0 + (h4 << 2));
            float4 v = LD4(e0 + 64 + (h4 << 2));
            d0 += u.x * f[h4 * 4 + 0]; d0 += u.y * f[h4 * 4 + 1];
            d0 += u.z * f[h4 * 4 + 2]; d0 += u.w * f[h4 * 4 + 3];
            d1 += v.x * f[h4 * 4 + 0]; d1 += v.y * f[h4 * 4 + 1];
            d1 += v.z * f[h4 * 4 + 2]; d1 += v.w * f[h4 * 4 + 3];
        }
        float s0 = en[kl] - 2.f * d0;
        float s1 = en[kl + 1] - 2.f * d1;
        if (s0 < best) { best = s0; bk = kl; }
        if (s1 < best) { best = s1; bk = kl + 1; }
    }
    pscore[row * 16 + chunk] = best;
    pidx[row * 16 + chunk] = chunk * 128 + bk;
}

// ---------------------------------------------------------------- vq reduce: final argmin, quant scatter, loss
__global__ __launch_bounds__(256) void k_vqreduce(const float* __restrict__ enc, const float* __restrict__ emb,
                                                  const float* __restrict__ pscore, const int* __restrict__ pidx,
                                                  float* __restrict__ qdec, float* __restrict__ loss) {
    int row = blockIdx.x * 256 + threadIdx.x;
    int c = row & 63, w = (row >> 6) & 63, b = row >> 12;
    float best = pscore[row * 16]; int bk = pidx[row * 16];
    #pragma unroll
    for (int ch = 1; ch < 16; ++ch) {         // ascending chunk + strict < == jnp.argmin first-min
        float s = pscore[row * 16 + ch];
        int k = pidx[row * 16 + ch];
        if (s < best) { best = s; bk = k; }
    }
    const float* e = emb + bk * 64;
    const float* fs = enc + b * 262144 + w * 64 + c;
    float* qd = qdec + b * 262144 + w * 64 + c;
    float ls = 0.f;
    #pragma unroll
    for (int h = 0; h < 64; ++h) {
        float ev = e[h];
        float fv = fs[h * 4096];
        float d = ev - fv;
        ls += d * d;
        qd[h * 4096] = ev;                    // qdec[b,h,w,c] = emb[idx][h]
    }
    #pragma unroll
    for (int off = 32; off; off >>= 1) ls += __shfl_xor(ls, off, 64);
    if ((threadIdx.x & 63) == 0) atomicAdd(loss, ls);
}

// ---------------------------------------------------------------- deconv1: qdec[16,64,64,64] -> g[4,128,128,256] (batch chunk)
// conv_transpose 4x4 s2 SAME: pad_a=pad_b=2, out[y,x,o] = sum over h=(y-2+ky)/2 even taps. leaky.
__global__ __launch_bounds__(256) void k_deconv1(const float* __restrict__ qdec, const float* __restrict__ dw1,
                                                 const float* __restrict__ db1, float* __restrict__ g, int b0) {
    __shared__ float smem[1024]; // [lh 4][lw 4][c 64]
    int bx = blockIdx.x;
    int xg = bx & 31, yg = (bx >> 5) & 31, bl = bx >> 10;
    int b = b0 + bl;
    int x0 = xg << 2, y0 = yg << 2;
    int m0 = yg << 1, n0 = xg << 1;
    int tid = threadIdx.x;
    {
        int e = tid << 2;
        int cc = e & 63, sp = e >> 6;
        int lh = sp >> 2, lw = sp & 3;
        int hh = m0 - 1 + lh, wwc = n0 - 1 + lw;
        float4 v = {0,0,0,0};
        if ((unsigned)hh < 64u && (unsigned)wwc < 64u)
            v = LD4(qdec + ((b * 64 + hh) * 64 + wwc) * 64 + cc);
        *(float4*)(smem + e) = v;
    }
    __syncthreads();
    int og = (tid & 63) << 2;
    int pg = tid >> 6;           // out row within tile (wave-uniform)
    int par = pg & 1;
    int lhb = (pg + 1) >> 1;
    float4 a0 = {0,0,0,0}, a1 = a0, a2 = a0, a3 = a0;
    #pragma unroll
    for (int tky = 0; tky < 2; ++tky) {
        int ky = par + 2 * tky;
        int lh = lhb + tky;
        #pragma unroll
        for (int tkx = 0; tkx < 2; ++tkx) {
            const float* wE = dw1 + ((ky * 4 + 2 * tkx) * 64) * 256 + og;       // even-x taps
            const float* wO = dw1 + ((ky * 4 + 2 * tkx + 1) * 64) * 256 + og;   // odd-x taps
            const float* l0 = smem + (lh * 4 + tkx) * 64;        // px0
            const float* l1 = l0 + 64;                           // px1, px2
            const float* l3 = l0 + 128;                          // px3
            #pragma unroll 2
            for (int i = 0; i < 64; i += 4) {
                float4 we0 = LD4(wE + (i + 0) * 256), we1 = LD4(wE + (i + 1) * 256),
                       we2 = LD4(wE + (i + 2) * 256), we3 = LD4(wE + (i + 3) * 256);
                float4 wo0 = LD4(wO + (i + 0) * 256), wo1 = LD4(wO + (i + 1) * 256),
                       wo2 = LD4(wO + (i + 2) * 256), wo3 = LD4(wO + (i + 3) * 256);
                float4 iA = LD4(l0 + i), iB = LD4(l1 + i), iC = LD4(l3 + i);
                FMA4(a0, iA.x, we0) FMA4(a0, iA.y, we1) FMA4(a0, iA.z, we2) FMA4(a0, iA.w, we3)
                FMA4(a1, iB.x, wo0) FMA4(a1, iB.y, wo1) FMA4(a1, iB.z, wo2) FMA4(a1, iB.w, wo3)
                FMA4(a2, iB.x, we0) FMA4(a2, iB.y, we1) FMA4(a2, iB.z, we2) FMA4(a2, iB.w, we3)
                FMA4(a3, iC.x, wo0) FMA4(a3, iC.y, wo1) FMA4(a3, iC.z, wo2) FMA4(a3, iC.w, wo3)
            }
        }
    }
    float4 bb = LD4(db1 + og);
    int ob = ((bl * 128 + (y0 + pg)) * 128 + x0) * 256 + og;
    STOREL(g + ob,       a0, bb)
    STOREL(g + ob + 256, a1, bb)
    STOREL(g + ob + 512, a2, bb)
    STOREL(g + ob + 768, a3, bb)
}

// ---------------------------------------------------------------- deconv2: g chunk -> recon[4,256,256,3], tanh
__global__ __launch_bounds__(256) void k_deconv2(const float* __restrict__ g, const float* __restrict__ dw2T,
                                                 const float* __restrict__ db2, float* __restrict__ out,
                                                 const float* __restrict__ loss, int b0, int write_loss) {
    int p = blockIdx.x * 256 + threadIdx.x;   // pixel within chunk (4*65536)
    int x = p & 255, y = (p >> 8) & 255, bl = p >> 16;
    int b = b0 + bl;
    float a0 = db2[0], a1 = db2[1], a2 = db2[2];
    #pragma unroll
    for (int tky = 0; tky < 2; ++tky) {
        int ky = (y & 1) + 2 * tky;
        int h = (y - 2 + ky) >> 1;
        if ((unsigned)h >= 128u) continue;
        #pragma unroll
        for (int tkx = 0; tkx < 2; ++tkx) {
            int kx = (x & 1) + 2 * tkx;
            int w = (x - 2 + kx) >> 1;
            if ((unsigned)w >= 128u) continue;
            const float* gb = g + ((bl * 128 + h) * 128 + w) * 256;
            int kk = ky * 4 + kx;
            const float* wr = dw2T + kk * 3 * 256;
            #pragma unroll 4
            for (int i = 0; i < 256; i += 4) {
                float4 gv = LD4(gb + i);
                float4 wa = LD4(wr + i);
                float4 wb = LD4(wr + 256 + i);
                float4 wc = LD4(wr + 512 + i);
                a0 += gv.x * wa.x + gv.y * wa.y + gv.z * wa.z + gv.w * wa.w;
                a1 += gv.x * wb.x + gv.y * wb.y + gv.z * wb.z + gv.w * wb.w;
                a2 += gv.x * wc.x + gv.y * wc.y + gv.z * wc.z + gv.w * wc.w;
            }
        }
    }
    int ob = (b * 65536 + (y << 8) + x) * 3;
    out[ob]     = tanhf(a0);
    out[ob + 1] = tanhf(a1);
    out[ob + 2] = tanhf(a2);
    if (write_loss && blockIdx.x == 0 && threadIdx.x == 0)
        out[3145728] = loss[0] * (1.25f / 4194304.f);
}

// ---------------------------------------------------------------- launch
extern "C" void kernel_launch(void* const* d_in, const int* in_sizes, int n_in,
                              void* d_out, int out_size, void* d_ws, size_t ws_size,
                              hipStream_t stream) {
    const float* x   = (const float*)d_in[0];
    const float* emb = (const float*)d_in[1];
    const float* w1  = (const float*)d_in[2];
    const float* b1  = (const float*)d_in[3];
    const float* w2  = (const float*)d_in[4];
    const float* b2  = (const float*)d_in[5];
    const float* w3  = (const float*)d_in[6];
    const float* b3  = (const float*)d_in[7];
    const float* dw1 = (const float*)d_in[8];
    const float* db1 = (const float*)d_in[9];
    const float* dw2 = (const float*)d_in[10];
    const float* db2 = (const float*)d_in[11];
    float* out = (float*)d_out;
    float* ws  = (float*)d_ws;

    if (ws_size < (size_t)60848144 * 4) return;  // need 243.4 MB scratch

    float* h1    = ws;                 // also reused as g (per-4-batch chunk)
    float* g     = ws;
    float* h2    = ws + 33554432;
    float* enc   = ws + 50331648;
    float* qdec  = ws + 54525952;
    float* w3T   = ws + 58720256;
    float* dw2T  = ws + 58736640;
    float* enorm = ws + 58748928;
    float* loss  = ws + 58750976;
    float* pscore= ws + 58750992;
    int*   pidx  = (int*)(ws + 59799568);

    k_prep   <<<120,   256, 0, stream>>>(w3, dw2, emb, w3T, dw2T, enorm, loss);
    k_conv1  <<<65536, 128, 0, stream>>>(x, w1, b1, h1);
    k_conv2  <<<4096,  256, 0, stream>>>(h1, w2, b2, h2);
    k_conv3  <<<16384, 256, 0, stream>>>(h2, w3T, b3, enc);
    k_vqdist <<<4096,  256, 0, stream>>>(enc, emb, enorm, pscore, pidx);
    k_vqreduce<<<256,  256, 0, stream>>>(enc, emb, pscore, pidx, qdec, loss);
    for (int b0 = 0; b0 < 16; b0 += 4) {
        k_deconv1<<<4096, 256, 0, stream>>>(qdec, dw1, db1, g, b0);
        k_deconv2<<<1024, 256, 0, stream>>>(g, dw2T, db2, out, loss, b0, (b0 == 12) ? 1 : 0);
    }
}